// Round 2
// baseline (251.668 us; speedup 1.0000x reference)
//
#include <hip/hip_runtime.h>

typedef unsigned int u32;

#define BN 32
#define CC 192
#define HH 64
#define WW 64
#define HWSZ (HH*WW)            // 4096
#define OHH 32
#define OWW 32
#define NVALID_SCALE 131072.0f  // BN*HH*WW per channel
#define PLH 65                  // rows: ih in [-1,63] -> r = ih+1
#define PLW2 66                 // cols: iw in [-1,63] -> c = iw+2 ; col 0 = unused pad
#define PLSZ (PLH*PLW2)         // 4290 words/plane (8B-aligned interior pairs)
#define NPLANE (12*BN)          // 2 br * 6 words * 32 n = 384 planes
#define NSTATS (CC*BN)          // 6144 stat blocks
#define NPW (2*CC)              // 384 weight-pack blocks
#define WROW 56                 // padded weight row (words): 224 B, 16B-aligned

// ---------------- K1 (fused front): stats + weight-pack + halo-zero ----------------
__global__ __launch_bounds__(256) void k_front(const float* __restrict__ x,
        float* __restrict__ partial,
        const float* __restrict__ w1, const float* __restrict__ w2,
        u32* __restrict__ wp, u32* __restrict__ wsum,
        u32* __restrict__ act) {
    __shared__ float red[8];
    __shared__ float wl[CC * 9];
    __shared__ u32 ww[54];
    int blk = blockIdx.x;
    int tid = threadIdx.x;
    if (blk < NSTATS) {
        int c = blk >> 5, n = blk & 31;
        const float4* p = (const float4*)(x + ((size_t)(n * CC + c) << 12));
        float s = 0.f, s2 = 0.f;
#pragma unroll
        for (int k = 0; k < 4; ++k) {
            float4 f = p[tid + 256 * k];
            s  += f.x + f.y + f.z + f.w;
            s2 += f.x * f.x + f.y * f.y + f.z * f.z + f.w * f.w;
        }
#pragma unroll
        for (int off = 32; off > 0; off >>= 1) {
            s  += __shfl_down(s, off, 64);
            s2 += __shfl_down(s2, off, 64);
        }
        int wv = tid >> 6, ln = tid & 63;
        if (ln == 0) { red[wv * 2] = s; red[wv * 2 + 1] = s2; }
        __syncthreads();
        if (tid == 0) {
            partial[blk * 2]     = red[0] + red[2] + red[4] + red[6];
            partial[blk * 2 + 1] = red[1] + red[3] + red[5] + red[7];
        }
    } else if (blk < NSTATS + NPW) {
        int b  = blk - NSTATS;
        int br = b / CC, oc = b - br * CC;
        const float* W = (br ? w2 : w1) + (size_t)oc * CC * 9;
        for (int i = tid; i < CC * 9; i += 256) wl[i] = W[i];
        __syncthreads();
        if (tid < WROW) {
            u32 word = 0;
            if (tid < 54) {
                int w6 = tid % 6, pos = tid / 6;
#pragma unroll
                for (int bb = 0; bb < 32; ++bb) {
                    if (wl[(w6 * 32 + bb) * 9 + pos] > 0.f) word |= (1u << bb);
                }
                ww[tid] = word;
            }
            wp[(size_t)b * WROW + tid] = word;   // pad words 54,55 = 0
        }
        __syncthreads();
        if (tid == 0) {
            int Wt[9];
#pragma unroll
            for (int t = 0; t < 9; ++t) {
                int s = 0;
#pragma unroll
                for (int w6 = 0; w6 < 6; ++w6) s += __popc(ww[t * 6 + w6]);
                Wt[t] = s;
            }
            wsum[b * 4 + 0] = (u32)(Wt[0] + Wt[1] + Wt[2]);  // top row kh=0
            wsum[b * 4 + 1] = (u32)(Wt[0] + Wt[3] + Wt[6]);  // left col kw=0
            wsum[b * 4 + 2] = (u32)Wt[0];                    // corner
            wsum[b * 4 + 3] = 0;
        }
    } else {
        int plane = blk - NSTATS - NPW;
        u32* pl = act + (size_t)plane * PLSZ;
        if (tid < PLW2) pl[tid] = 0;                             // row ih=-1 (r=0)
        else if (tid < PLW2 + 64) pl[(tid - PLW2 + 1) * PLW2 + 1] = 0;  // col iw=-1 rows 1..64
    }
}

// ---------------- K2: finalize BN coefs (both branches), 1 block/channel ----------------
__global__ __launch_bounds__(64) void k_coef(const float* __restrict__ partial,
        const float* __restrict__ g1, const float* __restrict__ b1,
        const float* __restrict__ g2, const float* __restrict__ b2,
        float* __restrict__ coef) {
    int c = blockIdx.x;
    int t = threadIdx.x;
    int half = t >> 5, i = t & 31;
    float v = partial[(c * 32 + i) * 2 + half];
#pragma unroll
    for (int off = 16; off > 0; off >>= 1) v += __shfl_down(v, off, 32);
    float S2 = __shfl(v, 32, 64);   // lane 32 holds sumsq reduction
    if (t == 0) {
        float S = v;
        const float inv = 1.0f / NVALID_SCALE;
        float mu  = S * inv;
        float var = S2 * inv - mu * mu;
        float r   = 1.0f / sqrtf(var + 1e-5f);
        float s1 = g1[c] * r, t1 = b1[c] - mu * s1;
        float s2 = g2[c] * r, t2 = b2[c] - mu * s2;
        ((float4*)coef)[c] = make_float4(s1, t1, s2, t2);
    }
}

// ---------------- K3: binarize + bit-pack acts (2x2 px/thread) + fused avgpool ----------------
__global__ __launch_bounds__(256) void k_pack_act(const float* __restrict__ x,
        const float* __restrict__ coef, u32* __restrict__ act,
        float* __restrict__ scb) {
    int bx = blockIdx.x;            // n*4 + q
    int g  = blockIdx.y;            // word group 0..5
    int n = bx >> 2, q = bx & 3;
    int tid = threadIdx.x;
    int ow = tid & 31, oh = (q << 3) + (tid >> 5);
    const float4* c4 = (const float4*)coef;
    const float* xb = x + (size_t)n * CC * HWSZ + (size_t)(2 * oh) * WW + 2 * ow;
    float* scp = scb + ((size_t)(n * CC + g * 32) * OHH + oh) * OWW + ow;
    u32 pk[8] = {0, 0, 0, 0, 0, 0, 0, 0};   // [br*4 + px]
#pragma unroll 4
    for (int bb = 0; bb < 32; ++bb) {
        int ch = g * 32 + bb;
        const float* p = xb + (size_t)ch * HWSZ;
        float2 r0 = *(const float2*)p;
        float2 r1 = *(const float2*)(p + WW);
        scp[(size_t)bb * (OHH * OWW)] = (r0.x + r0.y + r1.x + r1.y) * 0.25f;
        float4 cf = c4[ch];
        u32 bit = 1u << bb;
        if (r0.x * cf.x + cf.y > 0.f) pk[0] |= bit;
        if (r0.y * cf.x + cf.y > 0.f) pk[1] |= bit;
        if (r1.x * cf.x + cf.y > 0.f) pk[2] |= bit;
        if (r1.y * cf.x + cf.y > 0.f) pk[3] |= bit;
        if (r0.x * cf.z + cf.w > 0.f) pk[4] |= bit;
        if (r0.y * cf.z + cf.w > 0.f) pk[5] |= bit;
        if (r1.x * cf.z + cf.w > 0.f) pk[6] |= bit;
        if (r1.y * cf.z + cf.w > 0.f) pk[7] |= bit;
    }
    size_t o00 = (size_t)(2 * oh + 1) * PLW2 + (2 * ow + 2);   // even -> 8B aligned
    u32* a1 = act + ((size_t)(0 * 6 + g) * BN + n) * PLSZ + o00;
    u32* a2 = act + ((size_t)(1 * 6 + g) * BN + n) * PLSZ + o00;
    *(uint2*)a1            = make_uint2(pk[0], pk[1]);
    *(uint2*)(a1 + PLW2)   = make_uint2(pk[2], pk[3]);
    *(uint2*)a2            = make_uint2(pk[4], pk[5]);
    *(uint2*)(a2 + PLW2)   = make_uint2(pk[6], pk[7]);
}

// ---------------- K4: XNOR conv + bias + relu + precomputed shortcut ----------------
// Weights as 14x uint4 per (oc,br) (padded 56-word rows); wsum as 1x uint4/oc.
__global__ __launch_bounds__(256) void k_conv(
        const u32* __restrict__ act, const u32* __restrict__ wp,
        const uint4* __restrict__ wsum4, const float* __restrict__ scb,
        const float* __restrict__ bias1, const float* __restrict__ bias2,
        float* __restrict__ out) {
    int b    = blockIdx.x;
    int tile = b >> 2;                  // (n, ohp)
    int n    = tile >> 4, ohp = tile & 15;
    int wid  = __builtin_amdgcn_readfirstlane((int)(threadIdx.x >> 6));
    int ocbase = ((b & 3) * 4 + wid) * 12;   // 16 groups of 12 oc
    int lane = threadIdx.x & 63;
    int ow = lane & 31, lh = lane >> 5;
    int oh = 2 * ohp + lh;
    int lbase = (2 * oh) * PLW2 + 2 * ow + 1;   // tap (kh=0,kw=0)
    int topE  = (oh == 0), leftE = (ow == 0);
    int nv192 = CC * ((topE ? 2 : 3) * (leftE ? 2 : 3));
    float sc[12];
#pragma unroll 1
    for (int br = 0; br < 2; ++br) {
        // act fragments: a[t*6+w6], padded to 56 with zeros (match weight pad)
        u32 a[WROW];
        const u32* ap = act + ((size_t)(br * 6) * BN + n) * PLSZ + lbase;
#pragma unroll
        for (int w6 = 0; w6 < 6; ++w6) {
            const u32* app = ap + (size_t)w6 * (BN * PLSZ);
#pragma unroll
            for (int t = 0; t < 9; ++t) {
                a[t * 6 + w6] = app[(t / 3) * PLW2 + (t % 3)];
            }
        }
        a[54] = 0u; a[55] = 0u;
        const uint4*  wq4 = (const uint4*)(wp + (size_t)(br * CC + ocbase) * WROW);
        const uint4*  ws4 = wsum4 + (br * CC + ocbase);
        const float*  bsp = (br ? bias2 : bias1) + ocbase;
#pragma unroll 1
        for (int j = 0; j < 12; ++j) {
            const uint4* wr = wq4 + j * (WROW / 4);
            int p = 0;
#pragma unroll
            for (int k = 0; k < WROW / 4; ++k) {
                uint4 w4 = wr[k];
                p += __popc(a[4 * k + 0] ^ w4.x);
                p += __popc(a[4 * k + 1] ^ w4.y);
                p += __popc(a[4 * k + 2] ^ w4.z);
                p += __popc(a[4 * k + 3] ^ w4.w);
            }
            uint4 wsv = ws4[j];
            int corr = (topE ? (int)wsv.x : 0) + (leftE ? (int)wsv.y : 0)
                     - ((topE & leftE) ? (int)wsv.z : 0);
            int dot = nv192 - 2 * p + 2 * corr;
            int oc = ocbase + j;
            float y = (float)dot + bsp[j];
            if (br == 0) {
                sc[j] = scb[((size_t)(n * CC + oc) * OHH + oh) * OWW + ow];
            }
            __builtin_nontemporal_store(fmaxf(y, 0.f) + sc[j],
                &out[((size_t)(n * 384 + br * CC + oc) * OHH + oh) * OWW + ow]);
        }
    }
}

extern "C" void kernel_launch(void* const* d_in, const int* in_sizes, int n_in,
                              void* d_out, int out_size, void* d_ws, size_t ws_size,
                              hipStream_t stream) {
    const float* x     = (const float*)d_in[0];
    const float* g1    = (const float*)d_in[1];
    const float* b1    = (const float*)d_in[2];
    const float* w1    = (const float*)d_in[3];
    const float* bias1 = (const float*)d_in[4];
    const float* g2    = (const float*)d_in[5];
    const float* b2    = (const float*)d_in[6];
    const float* w2    = (const float*)d_in[7];
    const float* bias2 = (const float*)d_in[8];
    float* out = (float*)d_out;
    char* ws = (char*)d_ws;
    // ws layout:
    float* partial = (float*)(ws);                // 12288 f     -> 49152 B
    float* coef    = (float*)(ws + 49152);        // 768 f       -> 3072 B   (end 52224)
    u32*   wp      = (u32*)  (ws + 52224);        // 2*192*56 u32-> 86016 B  (end 138240)
    u32*   wsum    = (u32*)  (ws + 138240);       // 1536 u32    -> 6144 B   (end 144384)
    float* scb     = (float*)(ws + 144384);       // 32*192*1024 f -> 25165824 B (end 25310208)
    u32*   act     = (u32*)  (ws + 25310208);     // 384*4290 u32  -> 6589440 B (end ~31.9 MB)

    hipLaunchKernelGGL(k_front,   dim3(NSTATS + NPW + NPLANE), dim3(256), 0, stream,
                       x, partial, w1, w2, wp, wsum, act);
    hipLaunchKernelGGL(k_coef,    dim3(CC),          dim3(64),  0, stream,
                       partial, g1, b1, g2, b2, coef);
    hipLaunchKernelGGL(k_pack_act, dim3(128, 6),     dim3(256), 0, stream,
                       x, coef, act, scb);
    hipLaunchKernelGGL(k_conv,    dim3(BN * 16 * 4), dim3(256), 0, stream,
                       act, wp, (const uint4*)wsum, scb, bias1, bias2, out);
}

// Round 3
// 242.818 us; speedup vs baseline: 1.0364x; 1.0364x over previous
//
#include <hip/hip_runtime.h>

typedef unsigned int u32;

#define BN 32
#define CC 192
#define HH 64
#define WW 64
#define HWSZ (HH*WW)            // 4096
#define OHH 32
#define OWW 32
#define NVALID_SCALE 131072.0f  // BN*HH*WW per channel
#define PLH 65                  // rows: ih in [-1,63] -> r = ih+1
#define PLW2 66                 // cols: iw in [-1,63] -> c = iw+2 ; col 0 = unused pad
#define PLSZ (PLH*PLW2)         // 4290 words/plane (8B-aligned interior pairs)
#define NPLANE (12*BN)          // 2 br * 6 words * 32 n = 384 planes
#define NSTATS (CC*BN)          // 6144 stat blocks
#define NPW (2*CC)              // 384 weight-pack blocks
#define WSTR 12                 // padded words per (w6,oc): taps 0..8 + 3 pad

// ---------------- K1 (fused front): stats + weight-pack + halo-zero ----------------
// weight layout: wp[((br*6 + w6)*CC + oc)*12 + tap], tap=kh*3+kw, pads 9..11 = 0
__global__ __launch_bounds__(256) void k_front(const float* __restrict__ x,
        float* __restrict__ partial,
        const float* __restrict__ w1, const float* __restrict__ w2,
        u32* __restrict__ wp, u32* __restrict__ wsum,
        u32* __restrict__ act) {
    __shared__ float red[8];
    __shared__ float wl[CC * 9];
    __shared__ u32 ww[54];              // [w6*9 + tap]
    int blk = blockIdx.x;
    int tid = threadIdx.x;
    if (blk < NSTATS) {
        int c = blk >> 5, n = blk & 31;
        const float4* p = (const float4*)(x + ((size_t)(n * CC + c) << 12));
        float s = 0.f, s2 = 0.f;
#pragma unroll
        for (int k = 0; k < 4; ++k) {
            float4 f = p[tid + 256 * k];
            s  += f.x + f.y + f.z + f.w;
            s2 += f.x * f.x + f.y * f.y + f.z * f.z + f.w * f.w;
        }
#pragma unroll
        for (int off = 32; off > 0; off >>= 1) {
            s  += __shfl_down(s, off, 64);
            s2 += __shfl_down(s2, off, 64);
        }
        int wv = tid >> 6, ln = tid & 63;
        if (ln == 0) { red[wv * 2] = s; red[wv * 2 + 1] = s2; }
        __syncthreads();
        if (tid == 0) {
            partial[blk * 2]     = red[0] + red[2] + red[4] + red[6];
            partial[blk * 2 + 1] = red[1] + red[3] + red[5] + red[7];
        }
    } else if (blk < NSTATS + NPW) {
        int b  = blk - NSTATS;
        int br = b / CC, oc = b - br * CC;
        const float* W = (br ? w2 : w1) + (size_t)oc * CC * 9;
        for (int i = tid; i < CC * 9; i += 256) wl[i] = W[i];
        __syncthreads();
        if (tid < 72) {
            int w6 = tid / 12, pos = tid % 12;
            u32 word = 0;
            if (pos < 9) {
#pragma unroll
                for (int bb = 0; bb < 32; ++bb) {
                    if (wl[(w6 * 32 + bb) * 9 + pos] > 0.f) word |= (1u << bb);
                }
                ww[w6 * 9 + pos] = word;
            }
            wp[((size_t)(br * 6 + w6) * CC + oc) * WSTR + pos] = word;
        }
        __syncthreads();
        if (tid == 0) {
            int Wt[9];
#pragma unroll
            for (int t = 0; t < 9; ++t) {
                int s = 0;
#pragma unroll
                for (int w6 = 0; w6 < 6; ++w6) s += __popc(ww[w6 * 9 + t]);
                Wt[t] = s;
            }
            wsum[b * 4 + 0] = (u32)(Wt[0] + Wt[1] + Wt[2]);  // top row kh=0
            wsum[b * 4 + 1] = (u32)(Wt[0] + Wt[3] + Wt[6]);  // left col kw=0
            wsum[b * 4 + 2] = (u32)Wt[0];                    // corner
            wsum[b * 4 + 3] = 0;
        }
    } else {
        int plane = blk - NSTATS - NPW;
        u32* pl = act + (size_t)plane * PLSZ;
        if (tid < PLW2) pl[tid] = 0;                             // row ih=-1 (r=0)
        else if (tid < PLW2 + 64) pl[(tid - PLW2 + 1) * PLW2 + 1] = 0;  // col iw=-1 rows 1..64
    }
}

// ---------------- K2: finalize BN coefs (both branches), 1 block/channel ----------------
__global__ __launch_bounds__(64) void k_coef(const float* __restrict__ partial,
        const float* __restrict__ g1, const float* __restrict__ b1,
        const float* __restrict__ g2, const float* __restrict__ b2,
        float* __restrict__ coef) {
    int c = blockIdx.x;
    int t = threadIdx.x;
    int half = t >> 5, i = t & 31;
    float v = partial[(c * 32 + i) * 2 + half];
#pragma unroll
    for (int off = 16; off > 0; off >>= 1) v += __shfl_down(v, off, 32);
    float S2 = __shfl(v, 32, 64);   // lane 32 holds sumsq reduction
    if (t == 0) {
        float S = v;
        const float inv = 1.0f / NVALID_SCALE;
        float mu  = S * inv;
        float var = S2 * inv - mu * mu;
        float r   = 1.0f / sqrtf(var + 1e-5f);
        float s1 = g1[c] * r, t1 = b1[c] - mu * s1;
        float s2 = g2[c] * r, t2 = b2[c] - mu * s2;
        ((float4*)coef)[c] = make_float4(s1, t1, s2, t2);
    }
}

// ---------------- K3: binarize + bit-pack acts (2x2 px/thread) + fused avgpool ----------------
__global__ __launch_bounds__(256) void k_pack_act(const float* __restrict__ x,
        const float* __restrict__ coef, u32* __restrict__ act,
        float* __restrict__ scb) {
    int bx = blockIdx.x;            // n*4 + q
    int g  = blockIdx.y;            // word group 0..5
    int n = bx >> 2, q = bx & 3;
    int tid = threadIdx.x;
    int ow = tid & 31, oh = (q << 3) + (tid >> 5);
    const float4* c4 = (const float4*)coef;
    const float* xb = x + (size_t)n * CC * HWSZ + (size_t)(2 * oh) * WW + 2 * ow;
    float* scp = scb + ((size_t)(n * CC + g * 32) * OHH + oh) * OWW + ow;
    u32 pk[8] = {0, 0, 0, 0, 0, 0, 0, 0};   // [br*4 + px]
#pragma unroll 4
    for (int bb = 0; bb < 32; ++bb) {
        int ch = g * 32 + bb;
        const float* p = xb + (size_t)ch * HWSZ;
        float2 r0 = *(const float2*)p;
        float2 r1 = *(const float2*)(p + WW);
        scp[(size_t)bb * (OHH * OWW)] = (r0.x + r0.y + r1.x + r1.y) * 0.25f;
        float4 cf = c4[ch];
        u32 bit = 1u << bb;
        if (r0.x * cf.x + cf.y > 0.f) pk[0] |= bit;
        if (r0.y * cf.x + cf.y > 0.f) pk[1] |= bit;
        if (r1.x * cf.x + cf.y > 0.f) pk[2] |= bit;
        if (r1.y * cf.x + cf.y > 0.f) pk[3] |= bit;
        if (r0.x * cf.z + cf.w > 0.f) pk[4] |= bit;
        if (r0.y * cf.z + cf.w > 0.f) pk[5] |= bit;
        if (r1.x * cf.z + cf.w > 0.f) pk[6] |= bit;
        if (r1.y * cf.z + cf.w > 0.f) pk[7] |= bit;
    }
    size_t o00 = (size_t)(2 * oh + 1) * PLW2 + (2 * ow + 2);   // even -> 8B aligned
    u32* a1 = act + ((size_t)(0 * 6 + g) * BN + n) * PLSZ + o00;
    u32* a2 = act + ((size_t)(1 * 6 + g) * BN + n) * PLSZ + o00;
    *(uint2*)a1            = make_uint2(pk[0], pk[1]);
    *(uint2*)(a1 + PLW2)   = make_uint2(pk[2], pk[3]);
    *(uint2*)a2            = make_uint2(pk[4], pk[5]);
    *(uint2*)(a2 + PLW2)   = make_uint2(pk[6], pk[7]);
}

// ---------------- K4: XNOR conv + bias + relu + precomputed shortcut ----------------
// w6-outer loop: 9 live act words + 12 persistent accumulators -> stays in arch VGPRs
// (previous version's a[54..56] array was silently parked in AGPRs: VGPR_Count=48,
//  ~1450 extra v_accvgpr moves/thread -> 2.3x VALU inflation)
__global__ __launch_bounds__(256) void k_conv(
        const u32* __restrict__ act, const u32* __restrict__ wp,
        const uint4* __restrict__ wsum4, const float* __restrict__ scb,
        const float* __restrict__ bias1, const float* __restrict__ bias2,
        float* __restrict__ out) {
    int b    = blockIdx.x;
    int tile = b >> 2;                  // (n, ohp)
    int n    = tile >> 4, ohp = tile & 15;
    int wid  = __builtin_amdgcn_readfirstlane((int)(threadIdx.x >> 6));
    int ocbase = ((b & 3) * 4 + wid) * 12;   // 16 groups of 12 oc
    int lane = threadIdx.x & 63;
    int ow = lane & 31, lh = lane >> 5;
    int oh = 2 * ohp + lh;
    int lbase = (2 * oh) * PLW2 + 2 * ow + 1;   // tap (kh=0,kw=0): row 2oh, col 2ow+1
    int topE  = (oh == 0), leftE = (ow == 0);
    int nv192 = CC * ((topE ? 2 : 3) * (leftE ? 2 : 3));
#pragma unroll 1
    for (int br = 0; br < 2; ++br) {
        int p[12];
#pragma unroll
        for (int j = 0; j < 12; ++j) p[j] = 0;
        const u32* ap  = act + ((size_t)(br * 6) * BN + n) * PLSZ + lbase;
        const u32* wqb = wp + ((size_t)(br * 6) * CC + ocbase) * WSTR;
#pragma unroll 2
        for (int w6 = 0; w6 < 6; ++w6) {
            const u32* app = ap + (size_t)w6 * (BN * PLSZ);
            u32 a[9];
#pragma unroll
            for (int t = 0; t < 9; ++t) a[t] = app[(t / 3) * PLW2 + (t % 3)];
            const u32* wr = wqb + (size_t)w6 * (CC * WSTR);
#pragma unroll
            for (int j = 0; j < 12; ++j) {
#pragma unroll
                for (int t = 0; t < 9; ++t) {
                    p[j] += __popc(a[t] ^ wr[j * WSTR + t]);
                }
            }
        }
        const uint4*  ws4 = wsum4 + (br * CC + ocbase);
        const float*  bsp = (br ? bias2 : bias1) + ocbase;
#pragma unroll
        for (int j = 0; j < 12; ++j) {
            uint4 wsv = ws4[j];
            int corr = (topE ? (int)wsv.x : 0) + (leftE ? (int)wsv.y : 0)
                     - ((topE & leftE) ? (int)wsv.z : 0);
            int dot = nv192 - 2 * p[j] + 2 * corr;
            int oc = ocbase + j;
            float y = (float)dot + bsp[j];
            float sc = scb[((size_t)(n * CC + oc) * OHH + oh) * OWW + ow];
            __builtin_nontemporal_store(fmaxf(y, 0.f) + sc,
                &out[((size_t)(n * 384 + br * CC + oc) * OHH + oh) * OWW + ow]);
        }
    }
}

extern "C" void kernel_launch(void* const* d_in, const int* in_sizes, int n_in,
                              void* d_out, int out_size, void* d_ws, size_t ws_size,
                              hipStream_t stream) {
    const float* x     = (const float*)d_in[0];
    const float* g1    = (const float*)d_in[1];
    const float* b1    = (const float*)d_in[2];
    const float* w1    = (const float*)d_in[3];
    const float* bias1 = (const float*)d_in[4];
    const float* g2    = (const float*)d_in[5];
    const float* b2    = (const float*)d_in[6];
    const float* w2    = (const float*)d_in[7];
    const float* bias2 = (const float*)d_in[8];
    float* out = (float*)d_out;
    char* ws = (char*)d_ws;
    // ws layout:
    float* partial = (float*)(ws);                // 12288 f      -> 49152 B
    float* coef    = (float*)(ws + 49152);        // 768 f        -> 3072 B   (end 52224)
    u32*   wp      = (u32*)  (ws + 52224);        // 2*6*192*12 u32 -> 110592 B (end 162816)
    u32*   wsum    = (u32*)  (ws + 162816);       // 1536 u32     -> 6144 B   (end 168960)
    float* scb     = (float*)(ws + 168960);       // 32*192*1024 f -> 25165824 B (end 25334784)
    u32*   act     = (u32*)  (ws + 25334784);     // 384*4290 u32  -> 6589440 B (end ~31.9 MB)

    hipLaunchKernelGGL(k_front,   dim3(NSTATS + NPW + NPLANE), dim3(256), 0, stream,
                       x, partial, w1, w2, wp, wsum, act);
    hipLaunchKernelGGL(k_coef,    dim3(CC),          dim3(64),  0, stream,
                       partial, g1, b1, g2, b2, coef);
    hipLaunchKernelGGL(k_pack_act, dim3(128, 6),     dim3(256), 0, stream,
                       x, coef, act, scb);
    hipLaunchKernelGGL(k_conv,    dim3(BN * 16 * 4), dim3(256), 0, stream,
                       act, wp, (const uint4*)wsum, scb, bias1, bias2, out);
}

// Round 4
// 241.515 us; speedup vs baseline: 1.0420x; 1.0054x over previous
//
#include <hip/hip_runtime.h>

typedef unsigned int u32;

#define BN 32
#define CC 192
#define HH 64
#define WW 64
#define HWSZ (HH*WW)            // 4096
#define OHH 32
#define OWW 32
#define NVALID_SCALE 131072.0f  // BN*HH*WW per channel
#define PLH 65                  // rows: ih in [-1,63] -> r = ih+1
#define PLW2 66                 // cols: iw in [-1,63] -> c = iw+2 ; col 0 = unused pad
#define PLSZ (PLH*PLW2)         // 4290 words/plane (8B-aligned interior pairs)
#define NPLANE (12*BN)          // 2 br * 6 words * 32 n = 384 planes
#define NSTATS (CC*BN)          // 6144 stat blocks
#define NPW (2*CC)              // 384 weight-pack blocks
#define WSTR 12                 // padded words per (w6,oc): taps 0..8 + 3 pad

// ---------------- K1 (fused front): stats + weight-pack + halo-zero ----------------
// weight layout: wp[((br*6 + w6)*CC + oc)*12 + tap], tap=kh*3+kw, pads 9..11 = 0
__global__ __launch_bounds__(256) void k_front(const float* __restrict__ x,
        float* __restrict__ partial,
        const float* __restrict__ w1, const float* __restrict__ w2,
        u32* __restrict__ wp, u32* __restrict__ wsum,
        u32* __restrict__ act) {
    __shared__ float red[8];
    __shared__ float wl[CC * 9];
    __shared__ u32 ww[54];              // [w6*9 + tap]
    int blk = blockIdx.x;
    int tid = threadIdx.x;
    if (blk < NSTATS) {
        int c = blk >> 5, n = blk & 31;
        const float4* p = (const float4*)(x + ((size_t)(n * CC + c) << 12));
        float s = 0.f, s2 = 0.f;
#pragma unroll
        for (int k = 0; k < 4; ++k) {
            float4 f = p[tid + 256 * k];
            s  += f.x + f.y + f.z + f.w;
            s2 += f.x * f.x + f.y * f.y + f.z * f.z + f.w * f.w;
        }
#pragma unroll
        for (int off = 32; off > 0; off >>= 1) {
            s  += __shfl_down(s, off, 64);
            s2 += __shfl_down(s2, off, 64);
        }
        int wv = tid >> 6, ln = tid & 63;
        if (ln == 0) { red[wv * 2] = s; red[wv * 2 + 1] = s2; }
        __syncthreads();
        if (tid == 0) {
            partial[blk * 2]     = red[0] + red[2] + red[4] + red[6];
            partial[blk * 2 + 1] = red[1] + red[3] + red[5] + red[7];
        }
    } else if (blk < NSTATS + NPW) {
        int b  = blk - NSTATS;
        int br = b / CC, oc = b - br * CC;
        const float* W = (br ? w2 : w1) + (size_t)oc * CC * 9;
        for (int i = tid; i < CC * 9; i += 256) wl[i] = W[i];
        __syncthreads();
        if (tid < 72) {
            int w6 = tid / 12, pos = tid % 12;
            u32 word = 0;
            if (pos < 9) {
#pragma unroll
                for (int bb = 0; bb < 32; ++bb) {
                    if (wl[(w6 * 32 + bb) * 9 + pos] > 0.f) word |= (1u << bb);
                }
                ww[w6 * 9 + pos] = word;
            }
            wp[((size_t)(br * 6 + w6) * CC + oc) * WSTR + pos] = word;
        }
        __syncthreads();
        if (tid == 0) {
            int Wt[9];
#pragma unroll
            for (int t = 0; t < 9; ++t) {
                int s = 0;
#pragma unroll
                for (int w6 = 0; w6 < 6; ++w6) s += __popc(ww[w6 * 9 + t]);
                Wt[t] = s;
            }
            wsum[b * 4 + 0] = (u32)(Wt[0] + Wt[1] + Wt[2]);  // top row kh=0
            wsum[b * 4 + 1] = (u32)(Wt[0] + Wt[3] + Wt[6]);  // left col kw=0
            wsum[b * 4 + 2] = (u32)Wt[0];                    // corner
            wsum[b * 4 + 3] = 0;
        }
    } else {
        int plane = blk - NSTATS - NPW;
        u32* pl = act + (size_t)plane * PLSZ;
        if (tid < PLW2) pl[tid] = 0;                             // row ih=-1 (r=0)
        else if (tid < PLW2 + 64) pl[(tid - PLW2 + 1) * PLW2 + 1] = 0;  // col iw=-1 rows 1..64
    }
}

// ---------------- K2: coef(in-block) + binarize + bit-pack + fused avgpool ----------------
// Each block redundantly reduces BN coefs for its 32 channels from `partial`
// (8 KB L2-hot reads; kills the separate k_coef dispatch + gap).
// Pack split across half-waves: lanes 0-31 = ch 0..15, lanes 32-63 = ch 16..31,
// combined with one shfl_xor(32) -> 2x waves (24/CU) for latency hiding.
__global__ __launch_bounds__(256) void k_pack_act(const float* __restrict__ x,
        const float* __restrict__ partial,
        const float* __restrict__ g1, const float* __restrict__ b1,
        const float* __restrict__ g2, const float* __restrict__ b2,
        u32* __restrict__ act, float* __restrict__ scb) {
    int bx = blockIdx.x;            // n*8 + q
    int g  = blockIdx.y;            // word group 0..5
    int n = bx >> 3, q = bx & 7;
    int tid = threadIdx.x;
    __shared__ float4 cf_s[32];
    // --- BN coef for channels g*32 .. g*32+31 (4 threads per channel) ---
    if (tid < 128) {
        int ch = tid >> 2, k = tid & 3;     // ch groups of 4 never cross a wave
        int c = g * 32 + ch;
        int half = k >> 1, i0 = (k & 1) << 4;
        float s = 0.f;
#pragma unroll
        for (int i = 0; i < 16; ++i) s += partial[(c * 32 + i0 + i) * 2 + half];
        s += __shfl_xor(s, 1, 64);          // k pairs (0,1)->S, (2,3)->S2
        float S2 = __shfl_down(s, 2, 64);   // k==0 pulls k==2's sumsq total
        if (k == 0) {
            float S = s;
            const float inv = 1.0f / NVALID_SCALE;
            float mu  = S * inv;
            float var = S2 * inv - mu * mu;
            float r   = 1.0f / sqrtf(var + 1e-5f);
            float s1 = g1[c] * r, t1 = b1[c] - mu * s1;
            float s2 = g2[c] * r, t2 = b2[c] - mu * s2;
            cf_s[ch] = make_float4(s1, t1, s2, t2);
        }
    }
    __syncthreads();
    int wave = tid >> 6, lane = tid & 63;
    int ow = lane & 31, chh = lane >> 5;    // chh: 0 -> ch 0..15, 1 -> ch 16..31
    int oh = q * 4 + wave;
    const float* xb = x + (size_t)n * CC * HWSZ + (size_t)(2 * oh) * WW + 2 * ow;
    float* scp = scb + ((size_t)(n * CC + g * 32 + chh * 16) * OHH + oh) * OWW + ow;
    u32 pk[8] = {0, 0, 0, 0, 0, 0, 0, 0};   // [br*4 + px] px: (0,0)(0,1)(1,0)(1,1)
#pragma unroll 4
    for (int i = 0; i < 16; ++i) {
        int bb = chh * 16 + i;
        const float* p = xb + (size_t)(g * 32 + bb) * HWSZ;
        float2 r0 = *(const float2*)p;
        float2 r1 = *(const float2*)(p + WW);
        scp[(size_t)i * (OHH * OWW)] = (r0.x + r0.y + r1.x + r1.y) * 0.25f;
        float4 cf = cf_s[bb];
        u32 bit = 1u << bb;
        if (r0.x * cf.x + cf.y > 0.f) pk[0] |= bit;
        if (r0.y * cf.x + cf.y > 0.f) pk[1] |= bit;
        if (r1.x * cf.x + cf.y > 0.f) pk[2] |= bit;
        if (r1.y * cf.x + cf.y > 0.f) pk[3] |= bit;
        if (r0.x * cf.z + cf.w > 0.f) pk[4] |= bit;
        if (r0.y * cf.z + cf.w > 0.f) pk[5] |= bit;
        if (r1.x * cf.z + cf.w > 0.f) pk[6] |= bit;
        if (r1.y * cf.z + cf.w > 0.f) pk[7] |= bit;
    }
#pragma unroll
    for (int r = 0; r < 8; ++r) pk[r] |= __shfl_xor(pk[r], 32, 64);
    if (chh == 0) {
        size_t o00 = (size_t)(2 * oh + 1) * PLW2 + (2 * ow + 2);   // even -> 8B aligned
        u32* a1 = act + ((size_t)(0 * 6 + g) * BN + n) * PLSZ + o00;
        u32* a2 = act + ((size_t)(1 * 6 + g) * BN + n) * PLSZ + o00;
        *(uint2*)a1            = make_uint2(pk[0], pk[1]);
        *(uint2*)(a1 + PLW2)   = make_uint2(pk[2], pk[3]);
        *(uint2*)a2            = make_uint2(pk[4], pk[5]);
        *(uint2*)(a2 + PLW2)   = make_uint2(pk[6], pk[7]);
    }
}

// ---------------- K3: XNOR conv + bias + relu + precomputed shortcut ----------------
// w6-outer loop: 9 live act words + 12 persistent accumulators (stays in arch VGPRs;
// a large live act array gets parked in AGPRs -> 2x VALU inflation, round-2 lesson).
// sc[12] hoisted before the br loop: 12 loads (was 24) issued early for latency overlap.
__global__ __launch_bounds__(256) void k_conv(
        const u32* __restrict__ act, const u32* __restrict__ wp,
        const uint4* __restrict__ wsum4, const float* __restrict__ scb,
        const float* __restrict__ bias1, const float* __restrict__ bias2,
        float* __restrict__ out) {
    int b    = blockIdx.x;
    int tile = b >> 2;                  // (n, ohp)
    int n    = tile >> 4, ohp = tile & 15;
    int wid  = __builtin_amdgcn_readfirstlane((int)(threadIdx.x >> 6));
    int ocbase = ((b & 3) * 4 + wid) * 12;   // 16 groups of 12 oc
    int lane = threadIdx.x & 63;
    int ow = lane & 31, lh = lane >> 5;
    int oh = 2 * ohp + lh;
    int lbase = (2 * oh) * PLW2 + 2 * ow + 1;   // tap (kh=0,kw=0): row 2oh, col 2ow+1
    int topE  = (oh == 0), leftE = (ow == 0);
    int nv192 = CC * ((topE ? 2 : 3) * (leftE ? 2 : 3));
    float sc[12];
#pragma unroll
    for (int j = 0; j < 12; ++j) {
        sc[j] = scb[((size_t)(n * CC + ocbase + j) * OHH + oh) * OWW + ow];
    }
#pragma unroll 1
    for (int br = 0; br < 2; ++br) {
        int p[12];
#pragma unroll
        for (int j = 0; j < 12; ++j) p[j] = 0;
        const u32* ap  = act + ((size_t)(br * 6) * BN + n) * PLSZ + lbase;
        const u32* wqb = wp + ((size_t)(br * 6) * CC + ocbase) * WSTR;
#pragma unroll 2
        for (int w6 = 0; w6 < 6; ++w6) {
            const u32* app = ap + (size_t)w6 * (BN * PLSZ);
            u32 a[9];
#pragma unroll
            for (int t = 0; t < 9; ++t) a[t] = app[(t / 3) * PLW2 + (t % 3)];
            const u32* wr = wqb + (size_t)w6 * (CC * WSTR);
#pragma unroll
            for (int j = 0; j < 12; ++j) {
#pragma unroll
                for (int t = 0; t < 9; ++t) {
                    p[j] += __popc(a[t] ^ wr[j * WSTR + t]);
                }
            }
        }
        const uint4*  ws4 = wsum4 + (br * CC + ocbase);
        const float*  bsp = (br ? bias2 : bias1) + ocbase;
#pragma unroll
        for (int j = 0; j < 12; ++j) {
            uint4 wsv = ws4[j];
            int corr = (topE ? (int)wsv.x : 0) + (leftE ? (int)wsv.y : 0)
                     - ((topE & leftE) ? (int)wsv.z : 0);
            int dot = nv192 - 2 * p[j] + 2 * corr;
            int oc = ocbase + j;
            float y = (float)dot + bsp[j];
            __builtin_nontemporal_store(fmaxf(y, 0.f) + sc[j],
                &out[((size_t)(n * 384 + br * CC + oc) * OHH + oh) * OWW + ow]);
        }
    }
}

extern "C" void kernel_launch(void* const* d_in, const int* in_sizes, int n_in,
                              void* d_out, int out_size, void* d_ws, size_t ws_size,
                              hipStream_t stream) {
    const float* x     = (const float*)d_in[0];
    const float* g1    = (const float*)d_in[1];
    const float* b1    = (const float*)d_in[2];
    const float* w1    = (const float*)d_in[3];
    const float* bias1 = (const float*)d_in[4];
    const float* g2    = (const float*)d_in[5];
    const float* b2    = (const float*)d_in[6];
    const float* w2    = (const float*)d_in[7];
    const float* bias2 = (const float*)d_in[8];
    float* out = (float*)d_out;
    char* ws = (char*)d_ws;
    // ws layout:
    float* partial = (float*)(ws);                // 12288 f      -> 49152 B
    u32*   wp      = (u32*)  (ws + 49152);        // 2*6*192*12 u32 -> 110592 B (end 159744)
    u32*   wsum    = (u32*)  (ws + 159744);       // 1536 u32     -> 6144 B   (end 165888)
    float* scb     = (float*)(ws + 165888);       // 32*192*1024 f -> 25165824 B (end 25331712)
    u32*   act     = (u32*)  (ws + 25331712);     // 384*4290 u32  -> 6589440 B (end ~31.9 MB)

    hipLaunchKernelGGL(k_front,    dim3(NSTATS + NPW + NPLANE), dim3(256), 0, stream,
                       x, partial, w1, w2, wp, wsum, act);
    hipLaunchKernelGGL(k_pack_act, dim3(BN * 8, 6),  dim3(256), 0, stream,
                       x, partial, g1, b1, g2, b2, act, scb);
    hipLaunchKernelGGL(k_conv,     dim3(BN * 16 * 4), dim3(256), 0, stream,
                       act, wp, (const uint4*)wsum, scb, bias1, bias2, out);
}